// Round 11
// baseline (211.358 us; speedup 1.0000x reference)
//
#include <hip/hip_runtime.h>
#include <hip/hip_bf16.h>
#include <math.h>

typedef __attribute__((ext_vector_type(8))) short bf16x8;
typedef __attribute__((ext_vector_type(4))) float f32x4;

typedef const __attribute__((address_space(1))) unsigned int guint;
typedef __attribute__((address_space(3))) unsigned int luint;

static __device__ __forceinline__ short f2bf(float f) {
    union { float f; unsigned u; } a; a.f = f;
    unsigned r = 0x7FFFu + ((a.u >> 16) & 1u);
    return (short)((a.u + r) >> 16);
}
static __device__ __forceinline__ float bf2f(short s) {
    union { unsigned u; float f; } a;
    a.u = ((unsigned)(unsigned short)s) << 16;
    return a.f;
}

// ---------------------------------------------------------------------------
// Weight transpose: W (c,d) fp32 -> WT (d,c) bf16 * scale, 4 weights in z.
// ---------------------------------------------------------------------------
__global__ __launch_bounds__(256)
void transpose_w(const float* __restrict__ w0, const float* __restrict__ w1,
                 const float* __restrict__ w2, const float* __restrict__ w3,
                 short* __restrict__ outT, float qscale)
{
    __shared__ float ld[32][33];
    const float* W = (blockIdx.z == 0) ? w0 : (blockIdx.z == 1) ? w1
                   : (blockIdx.z == 2) ? w2 : w3;
    const float sc = (blockIdx.z == 0) ? qscale : 1.f;
    short* O = outT + (long long)blockIdx.z * 512 * 512;
    const int tx = threadIdx.x & 31, ty = threadIdx.x >> 5;
    const int c0 = blockIdx.y * 32, d0 = blockIdx.x * 32;
#pragma unroll
    for (int r = 0; r < 4; ++r)
        ld[ty + 8 * r][tx] = W[(long long)(c0 + ty + 8 * r) * 512 + d0 + tx];
    __syncthreads();
#pragma unroll
    for (int r = 0; r < 4; ++r)
        O[(long long)(d0 + ty + 8 * r) * 512 + c0 + tx] = f2bf(ld[tx][ty + 8 * r] * sc);
}

__global__ __launch_bounds__(256)
void concat_bias(const float* __restrict__ bq, const float* __restrict__ bk,
                 float* __restrict__ bqk, float qscale)
{
    int i = blockIdx.x * 256 + threadIdx.x;  // grid 4
    bqk[i] = (i < 512) ? bq[i] * qscale : bk[i - 512];
}

// ---------------------------------------------------------------------------
// GroupNorm stats: one block per (b,g); group = 16 ch x 1024 spatial.
// ---------------------------------------------------------------------------
__global__ __launch_bounds__(256)
void gn_stats(const float* __restrict__ x, float2* __restrict__ stats)
{
    const int bg = blockIdx.x;
    const float4* p = reinterpret_cast<const float4*>(x + (long long)bg * 16384);
    float s = 0.f, ss = 0.f;
    for (int i = threadIdx.x; i < 4096; i += 256) {
        float4 v = p[i];
        s  += v.x + v.y + v.z + v.w;
        ss += v.x * v.x + v.y * v.y + v.z * v.z + v.w * v.w;
    }
    __shared__ float rs[256], rss[256];
    rs[threadIdx.x] = s; rss[threadIdx.x] = ss;
    __syncthreads();
    for (int o = 128; o > 0; o >>= 1) {
        if (threadIdx.x < o) { rs[threadIdx.x] += rs[threadIdx.x + o];
                               rss[threadIdx.x] += rss[threadIdx.x + o]; }
        __syncthreads();
    }
    if (threadIdx.x == 0) {
        float mean = rs[0] * (1.f / 16384.f);
        float var  = rss[0] * (1.f / 16384.f) - mean * mean;
        stats[bg] = make_float2(mean, rsqrtf(var + 1e-6f));
    }
}

// ---------------------------------------------------------------------------
// GroupNorm apply + transpose: x (b,c,s) fp32 -> hn (b,s,c) bf16.
// ---------------------------------------------------------------------------
__global__ __launch_bounds__(256)
void gn_apply_t(const float* __restrict__ x, const float2* __restrict__ stats,
                const float* __restrict__ gamma, const float* __restrict__ beta,
                short* __restrict__ hn)
{
    __shared__ short lds[32 * 520];
    const int t = threadIdx.x;
    const int s0 = blockIdx.x * 32;
    const int b  = blockIdx.y;
#pragma unroll
    for (int i = 0; i < 16; ++i) {
        int qi = t + 256 * i;
        int c = qi >> 3, sc = qi & 7;
        float4 v = *reinterpret_cast<const float4*>(
            x + ((long long)(b * 512 + c)) * 1024 + s0 + sc * 4);
        float2 st = stats[b * 32 + (c >> 4)];
        float ga = gamma[c], be = beta[c];
        float m = st.x, r = st.y;
        lds[(sc * 4 + 0) * 520 + c] = f2bf((v.x - m) * r * ga + be);
        lds[(sc * 4 + 1) * 520 + c] = f2bf((v.y - m) * r * ga + be);
        lds[(sc * 4 + 2) * 520 + c] = f2bf((v.z - m) * r * ga + be);
        lds[(sc * 4 + 3) * 520 + c] = f2bf((v.w - m) * r * ga + be);
    }
    __syncthreads();
#pragma unroll
    for (int i = 0; i < 8; ++i) {
        int p = t + 256 * i;
        int s = p >> 6, j = p & 63;
        float4 v = *reinterpret_cast<const float4*>(&lds[s * 520 + j * 8]);
        *reinterpret_cast<float4*>(
            hn + ((long long)(b * 1024 + s0 + s)) * 512 + j * 8) = v;
    }
}

// ---------------------------------------------------------------------------
// NT GEMM, 256x256 / 8-wave / ONE phase + ONE barrier per K-tile (R11).
// R10 (de-fenced 2-phase) proved manual drains were the regression; R11
// halves the remaining barrier events: per K-tile {stage kt+1 (8 gload_lds,
// issued at tile top -> full-tile latency cover), 24 ds_read_b128, 64 MFMA
// (compiler-scheduled interior, no manual lgkm/setprio), sched_barrier,
// vmcnt(0) (loads landed ~2k cyc ago -> wait ~0), s_barrier, sched_barrier}.
// Safety: per-wave, compiler lgkm-waits before MFMAs guarantee all ds_reads
// returned before the wave's barrier (MFMA issue pinned pre-barrier by the
// sched_barrier); stages into buf^1 only execute after the previous barrier,
// so the DMA never overwrites a region still being read. vmcnt(0) before
// the barrier guarantees staged data visible to next tile's reads.
// Both-sides XOR swizzle (0 conflicts), XCD-aware grid remap, fused rowsum
// partials (EXPRS) / 4-partial divide (DIVROW4) epilogues as in R9/R10.
// ---------------------------------------------------------------------------
template<int BIAS_M, int BIAS_N, int RESID, int EXPRS, int DIVROW4>
__global__ __launch_bounds__(512, 1)
void nt_gemm(const short* __restrict__ A, const short* __restrict__ B,
             void* __restrict__ Cv,
             const float* __restrict__ biasM, const float* __restrict__ biasN,
             const float* __restrict__ resid, float* __restrict__ rs,
             float scale, int K, int lda, int ldb, int ldc,
             long long sA, long long sB, long long sC,
             int tilesM, int tilesPerBatch)
{
    __shared__ short lsA[2][2][128 * 64];   // [buf][Mhalf] 16 KB regions
    __shared__ short lsB[2][2][128 * 64];   // 128 KB total

    const int id = blockIdx.x;
    const int chunk = gridDim.x >> 3;    // grid % 8 == 0 by construction
    const int gid = (id & 7) * chunk + (id >> 3);
    const int bz = gid / tilesPerBatch;
    const int tt = gid - bz * tilesPerBatch;
    const int m0 = (tt % tilesM) * 256;
    const int n0 = (tt / tilesM) * 256;

    const int t = threadIdx.x;           // 0..511
    const int lane = t & 63;
    const int w = t >> 6;                // 0..7
    const int wrs = w >> 1;              // row strip 0..3 (32 rows/quadrant)
    const int wcs = w & 1;               // col strip 0..1 (64 cols/quadrant)
    const int lr16 = lane & 15, lkg = lane >> 4;
    const int sw = lr16 & 7;             // read-side swizzle key (row & 7)

    const int srow = t >> 3;             // 0..63
    const int scol = ((t & 7) ^ (srow & 7)) * 8;   // pre-swizzled source col
    const short* gA = A + (long long)bz * sA + (long long)(m0 + srow) * lda + scol;
    const short* gB = B + (long long)bz * sB + (long long)(n0 + srow) * ldb + scol;

    f32x4 acc[4][2][4];                  // [quadrant ah*2+bh][mi2][ni]
#pragma unroll
    for (int q = 0; q < 4; ++q)
#pragma unroll
        for (int i = 0; i < 2; ++i)
#pragma unroll
            for (int j = 0; j < 4; ++j) acc[q][i][j] = (f32x4){0.f, 0.f, 0.f, 0.f};

    const int nk = K >> 6;               // even (8 or 16)

#define STAGE_A(buf, h, kt)                                                    \
    {                                                                          \
        _Pragma("unroll")                                                      \
        for (int c = 0; c < 2; ++c)                                            \
            __builtin_amdgcn_global_load_lds(                                  \
                (guint*)(gA + (long long)((h) * 128 + 64 * c) * lda + (kt) * 64), \
                (luint*)&lsA[buf][h][t * 8 + 4096 * c], 16, 0, 0);             \
    }
#define STAGE_B(buf, h, kt)                                                    \
    {                                                                          \
        _Pragma("unroll")                                                      \
        for (int c = 0; c < 2; ++c)                                            \
            __builtin_amdgcn_global_load_lds(                                  \
                (guint*)(gB + (long long)((h) * 128 + 64 * c) * ldb + (kt) * 64), \
                (luint*)&lsB[buf][h][t * 8 + 4096 * c], 16, 0, 0);             \
    }

#define LDA_HALF(dst, buf, h)                                                  \
    _Pragma("unroll")                                                          \
    for (int mi2 = 0; mi2 < 2; ++mi2)                                          \
        _Pragma("unroll")                                                      \
        for (int ks = 0; ks < 2; ++ks)                                         \
            dst[mi2][ks] = *reinterpret_cast<const bf16x8*>(                   \
                &lsA[buf][h][(wrs * 32 + mi2 * 16 + lr16) * 64 +               \
                             (((ks * 4 + lkg) ^ sw) * 8)]);
#define LDB_HALF(dst, buf, h)                                                  \
    _Pragma("unroll")                                                          \
    for (int ni = 0; ni < 4; ++ni)                                             \
        _Pragma("unroll")                                                      \
        for (int ks = 0; ks < 2; ++ks)                                         \
            dst[ni][ks] = *reinterpret_cast<const bf16x8*>(                    \
                &lsB[buf][h][(wcs * 64 + ni * 16 + lr16) * 64 +                \
                             (((ks * 4 + lkg) ^ sw) * 8)]);

#define MFMAQ(q, Af, Bf)                                                       \
    _Pragma("unroll")                                                          \
    for (int ks = 0; ks < 2; ++ks)                                             \
        _Pragma("unroll")                                                      \
        for (int mi2 = 0; mi2 < 2; ++mi2)                                      \
            _Pragma("unroll")                                                  \
            for (int ni = 0; ni < 4; ++ni)                                     \
                acc[q][mi2][ni] = __builtin_amdgcn_mfma_f32_16x16x32_bf16(     \
                    Af[mi2][ks], Bf[ni][ks], acc[q][mi2][ni], 0, 0, 0);

#define TILE_END                                                               \
    __builtin_amdgcn_sched_barrier(0);                                         \
    asm volatile("s_waitcnt vmcnt(0)" ::: "memory");                           \
    __builtin_amdgcn_s_barrier();                                              \
    __builtin_amdgcn_sched_barrier(0)

#define FRAME(b, kt)                                                           \
    {                                                                          \
        bf16x8 a0[2][2], a1[2][2], b0f[4][2], b1f[4][2];                       \
        /* stage next tile first: full-tile latency cover */                   \
        STAGE_B((b) ^ 1, 0, (kt) + 1);                                         \
        STAGE_B((b) ^ 1, 1, (kt) + 1);                                         \
        STAGE_A((b) ^ 1, 0, (kt) + 1);                                         \
        STAGE_A((b) ^ 1, 1, (kt) + 1);                                         \
        /* whole K-tile: 24 ds_reads + 64 MFMA, compiler-scheduled */          \
        LDB_HALF(b0f, b, 0)                                                    \
        LDA_HALF(a0, b, 0)                                                     \
        MFMAQ(0, a0, b0f)                                                      \
        LDB_HALF(b1f, b, 1)                                                    \
        MFMAQ(1, a0, b1f)                                                      \
        LDA_HALF(a1, b, 1)                                                     \
        MFMAQ(2, a1, b0f)                                                      \
        MFMAQ(3, a1, b1f)                                                      \
        TILE_END;                                                              \
    }

    // prologue: stage tile0 (8 loads), drain, barrier.
    STAGE_B(0, 0, 0); STAGE_B(0, 1, 0); STAGE_A(0, 0, 0); STAGE_A(0, 1, 0);
    TILE_END;

    for (int kt = 0; kt < nk; kt += 2) {
        FRAME(0, kt)
        FRAME(1, kt + 1)
    }
    // (tail frame stages tile nk: overshoot reads land in adjacent allocated
    //  ws regions and are never consumed; lsA[1] scratch below is used only
    //  after a __syncthreads.)
#undef STAGE_A
#undef STAGE_B
#undef LDA_HALF
#undef LDB_HALF
#undef MFMAQ
#undef TILE_END
#undef FRAME

    // epilogue: D layout col=lane&15, row=(lane>>4)*4+reg (m89-verified)
    float psum[2][2][4];
    if (EXPRS) {
#pragma unroll
        for (int ah = 0; ah < 2; ++ah)
#pragma unroll
            for (int mi2 = 0; mi2 < 2; ++mi2)
#pragma unroll
                for (int j = 0; j < 4; ++j) psum[ah][mi2][j] = 0.f;
    }
#pragma unroll
    for (int ah = 0; ah < 2; ++ah) {
#pragma unroll
        for (int bh = 0; bh < 2; ++bh) {
#pragma unroll
            for (int mi2 = 0; mi2 < 2; ++mi2) {
                float addm[4], mul[4];
#pragma unroll
                for (int j = 0; j < 4; ++j) {
                    const int rrow = m0 + ah * 128 + wrs * 32 + mi2 * 16 + lkg * 4 + j;
                    addm[j] = BIAS_M ? biasM[rrow] : 0.f;
                    if (DIVROW4) {
                        const float* r4 = rs + (long long)bz * 4096 + rrow;
                        mul[j] = 1.f / (r4[0] + r4[1024] + r4[2048] + r4[3072]);
                    } else mul[j] = 1.f;
                }
#pragma unroll
                for (int ni = 0; ni < 4; ++ni) {
                    const int col = n0 + bh * 128 + wcs * 64 + ni * 16 + lr16;
                    float bn = BIAS_N ? biasN[col] : 0.f;
#pragma unroll
                    for (int j = 0; j < 4; ++j) {
                        const int rrow = m0 + ah * 128 + wrs * 32 + mi2 * 16 + lkg * 4 + j;
                        float v2 = acc[ah * 2 + bh][mi2][ni][j] + addm[j] + bn;
                        v2 *= scale;
                        if (EXPRS) { v2 = __expf(v2 - 8.f); psum[ah][mi2][j] += v2; }
                        if (DIVROW4) v2 *= mul[j];
                        const long long idx = (long long)rrow * ldc + col;
                        if (RESID) {
                            float* Cf = (float*)Cv + (long long)bz * sC;
                            Cf[idx] = v2 + resid[(long long)bz * sC + idx];
                        } else {
                            short* Cs = (short*)Cv + (long long)bz * sC;
                            Cs[idx] = f2bf(v2);
                        }
                    }
                }
            }
        }
    }
    if (EXPRS) {
        // rowsum partials: reduce over lr16 lanes (16 cols each of this
        // wave's 2x64-col strips), combine the two wcs waves via lsA[1]
        // scratch (dead region), write rs4[bz][n0/256][m0 + r].
#pragma unroll
        for (int ah = 0; ah < 2; ++ah)
#pragma unroll
            for (int mi2 = 0; mi2 < 2; ++mi2)
#pragma unroll
                for (int j = 0; j < 4; ++j) {
                    float v = psum[ah][mi2][j];
                    v += __shfl_xor(v, 1); v += __shfl_xor(v, 2);
                    v += __shfl_xor(v, 4); v += __shfl_xor(v, 8);
                    psum[ah][mi2][j] = v;
                }
        float* scr = (float*)&lsA[1][0][0];   // 2KB scratch (loop is done)
        __syncthreads();
        if (lr16 == 0) {
#pragma unroll
            for (int ah = 0; ah < 2; ++ah)
#pragma unroll
                for (int mi2 = 0; mi2 < 2; ++mi2)
#pragma unroll
                    for (int j = 0; j < 4; ++j)
                        scr[wcs * 256 + ah * 128 + wrs * 32 + mi2 * 16 + lkg * 4 + j]
                            = psum[ah][mi2][j];
        }
        __syncthreads();
        if (t < 256)
            rs[(long long)bz * 4096 + (n0 >> 8) * 1024 + m0 + t]
                = scr[t] + scr[256 + t];
    }
}

// ---------------------------------------------------------------------------
extern "C" void kernel_launch(void* const* d_in, const int* in_sizes, int n_in,
                              void* d_out, int out_size, void* d_ws, size_t ws_size,
                              hipStream_t stream)
{
    (void)in_sizes; (void)n_in; (void)out_size; (void)ws_size;
    const float* x     = (const float*)d_in[0];
    const float* gamma = (const float*)d_in[1];
    const float* beta  = (const float*)d_in[2];
    const float* Wq = (const float*)d_in[3];
    const float* bq = (const float*)d_in[4];
    const float* Wk = (const float*)d_in[5];
    const float* bk = (const float*)d_in[6];
    const float* Wv = (const float*)d_in[7];
    const float* bv = (const float*)d_in[8];
    const float* Wp = (const float*)d_in[9];
    const float* bp = (const float*)d_in[10];
    float* out = (float*)d_out;

    // Workspace (time-overlapped), ~162.6 MB:
    //   [0,64M):    expS (b,s,t) bf16; hn (b,s,c) bf16 in [0,32M) dies after
    //               the v-GEMM, before scores writes expS.
    //   [64,128M):  qk (b,s,1024) bf16; dies after scores; ho reuses [64,96M).
    //   [128,160M): v (b,c,t) bf16
    //   [160,162M): WT = {WqT*qs, WkT, WvT, WpT} (d,c) bf16
    //   [162M..):   stats (8K) | bqk (4K) | rs4 (b,4,1024) f32 (512K)
    char* ws = (char*)d_ws;
    short*  expS = (short*)ws;
    short*  hn   = (short*)ws;
    short*  qkb  = (short*)(ws + (64LL << 20));
    short*  vbuf = (short*)(ws + (128LL << 20));
    short*  wT   = (short*)(ws + (160LL << 20));
    float2* stats = (float2*)(ws + (162LL << 20));
    float*  bqk   = (float*)(ws + (162LL << 20) + (16 << 10));
    float*  rs4   = (float*)(ws + (162LL << 20) + (32 << 10));
    short*  ho    = qkb;

    const short* WqkT = wT;                  // rows 0-511: Wq^T*qs; 512-1023: Wk^T
    const short* WvT  = wT + 2 * 512 * 512;
    const short* WpT  = wT + 3 * 512 * 512;

    const float qscale = 0.044194173824159216f;  // 512^-0.5

    transpose_w<<<dim3(16, 16, 4), 256, 0, stream>>>(Wq, Wk, Wv, Wp, wT, qscale);
    concat_bias<<<dim3(4), 256, 0, stream>>>(bq, bk, bqk, qscale);
    gn_stats<<<dim3(1024), 256, 0, stream>>>(x, stats);
    gn_apply_t<<<dim3(32, 32), 256, 0, stream>>>(x, stats, gamma, beta, hn);

    // qk = hn @ [Wq*qs | Wk] + bqk : M=1024(s), N=1024(d'), K=512 -> 4x4x32
    nt_gemm<0, 1, 0, 0, 0><<<512, 512, 0, stream>>>(
        hn, WqkT, qkb, nullptr, bqk, nullptr, nullptr, 1.f,
        512, 512, 512, 1024, 1024 * 512, 0, 1024LL * 1024, 4, 16);
    // v (d,t) = WvT @ hn^T + bv : M=512(d), N=1024(t), K=512 -> 2x4x32
    nt_gemm<1, 0, 0, 0, 0><<<256, 512, 0, stream>>>(
        WvT, hn, vbuf, bv, nullptr, nullptr, nullptr, 1.f,
        512, 512, 512, 1024, 0, 1024 * 512, 512 * 1024, 2, 8);
    // expS (s,t) = exp(q @ k^T - 8) + rs4 partials : M=N=1024, K=512
    nt_gemm<0, 0, 0, 1, 0><<<512, 512, 0, stream>>>(
        qkb, qkb + 512, expS, nullptr, nullptr, nullptr, rs4, 1.f,
        512, 1024, 1024, 1024, 1024LL * 1024, 1024LL * 1024, 1024LL * 1024, 4, 16);
    // ho (s,c) = (expS @ v^T) / rowsum : M=1024(s), N=512(c), K=1024 -> 4x2x32
    nt_gemm<0, 0, 0, 0, 1><<<256, 512, 0, stream>>>(
        expS, vbuf, ho, nullptr, nullptr, nullptr, rs4, 1.f,
        1024, 1024, 1024, 512, 1024LL * 1024, 512 * 1024, 1024 * 512, 4, 8);
    // out (d,s) = WpT @ ho^T + bp + x : M=512(d), N=1024(s), K=512, fp32
    nt_gemm<1, 0, 1, 0, 0><<<256, 512, 0, stream>>>(
        WpT, ho, out, bp, nullptr, x, nullptr, 1.f,
        512, 512, 512, 1024, 0, 1024 * 512, 512LL * 1024, 2, 8);
}

// Round 12
// 201.929 us; speedup vs baseline: 1.0467x; 1.0467x over previous
//
#include <hip/hip_runtime.h>
#include <hip/hip_bf16.h>
#include <math.h>

typedef __attribute__((ext_vector_type(8))) short bf16x8;
typedef __attribute__((ext_vector_type(4))) float f32x4;

typedef const __attribute__((address_space(1))) unsigned int guint;
typedef __attribute__((address_space(3))) unsigned int luint;

static __device__ __forceinline__ short f2bf(float f) {
    union { float f; unsigned u; } a; a.f = f;
    unsigned r = 0x7FFFu + ((a.u >> 16) & 1u);
    return (short)((a.u + r) >> 16);
}
static __device__ __forceinline__ float bf2f(short s) {
    union { unsigned u; float f; } a;
    a.u = ((unsigned)(unsigned short)s) << 16;
    return a.f;
}

// ---------------------------------------------------------------------------
// Weight transpose: W (c,d) fp32 -> WT (d,c) bf16 * scale, 4 weights in z.
// ---------------------------------------------------------------------------
__global__ __launch_bounds__(256)
void transpose_w(const float* __restrict__ w0, const float* __restrict__ w1,
                 const float* __restrict__ w2, const float* __restrict__ w3,
                 short* __restrict__ outT, float qscale)
{
    __shared__ float ld[32][33];
    const float* W = (blockIdx.z == 0) ? w0 : (blockIdx.z == 1) ? w1
                   : (blockIdx.z == 2) ? w2 : w3;
    const float sc = (blockIdx.z == 0) ? qscale : 1.f;
    short* O = outT + (long long)blockIdx.z * 512 * 512;
    const int tx = threadIdx.x & 31, ty = threadIdx.x >> 5;
    const int c0 = blockIdx.y * 32, d0 = blockIdx.x * 32;
#pragma unroll
    for (int r = 0; r < 4; ++r)
        ld[ty + 8 * r][tx] = W[(long long)(c0 + ty + 8 * r) * 512 + d0 + tx];
    __syncthreads();
#pragma unroll
    for (int r = 0; r < 4; ++r)
        O[(long long)(d0 + ty + 8 * r) * 512 + c0 + tx] = f2bf(ld[tx][ty + 8 * r] * sc);
}

__global__ __launch_bounds__(256)
void concat_bias(const float* __restrict__ bq, const float* __restrict__ bk,
                 float* __restrict__ bqk, float qscale)
{
    int i = blockIdx.x * 256 + threadIdx.x;  // grid 4
    bqk[i] = (i < 512) ? bq[i] * qscale : bk[i - 512];
}

// ---------------------------------------------------------------------------
// FUSED GroupNorm: one block per (b,g); group = 16 ch x 1024 spatial = 64KB
// fp32, LDS-resident. Single x read (was 2 passes = 2x128MB reads).
// Output hn in BLOCKED layout [b][g][s][16c] (bf16): each block writes its
// 32KB contiguously & fully coalesced. GEMM hn-operand addressing adapted
// (16B chunks never straddle the 16-channel group boundary).
// ---------------------------------------------------------------------------
__global__ __launch_bounds__(256)
void gn_fused(const float* __restrict__ x, const float* __restrict__ gamma,
              const float* __restrict__ beta, short* __restrict__ hn)
{
    __shared__ float xs[16 * 1024];    // 64 KB
    __shared__ float red[256];
    const int bg = blockIdx.x;         // b*32+g
    const int g  = bg & 31;
    const int t  = threadIdx.x;
    const float4* px = reinterpret_cast<const float4*>(x + (long long)bg * 16384);
    float s = 0.f, ss = 0.f;
#pragma unroll
    for (int i = 0; i < 16; ++i) {
        float4 v = px[t + 256 * i];
        reinterpret_cast<float4*>(xs)[t + 256 * i] = v;
        s  += v.x + v.y + v.z + v.w;
        ss += v.x * v.x + v.y * v.y + v.z * v.z + v.w * v.w;
    }
    red[t] = s; __syncthreads();
    for (int o = 128; o > 0; o >>= 1) {
        if (t < o) red[t] += red[t + o];
        __syncthreads();
    }
    const float mean = red[0] * (1.f / 16384.f);
    __syncthreads();
    red[t] = ss; __syncthreads();
    for (int o = 128; o > 0; o >>= 1) {
        if (t < o) red[t] += red[t + o];
        __syncthreads();
    }
    const float var  = red[0] * (1.f / 16384.f) - mean * mean;
    const float rstd = rsqrtf(var + 1e-6f);

    const int half = t & 1;
    float ga[8], be[8];
#pragma unroll
    for (int cc = 0; cc < 8; ++cc) {
        ga[cc] = gamma[g * 16 + half * 8 + cc];
        be[cc] = beta[g * 16 + half * 8 + cc];
    }
    short* out = hn + (long long)bg * 16384;
#pragma unroll
    for (int it = 0; it < 8; ++it) {
        const int sidx = it * 128 + (t >> 1);
        bf16x8 o;
#pragma unroll
        for (int cc = 0; cc < 8; ++cc) {
            float v = xs[(half * 8 + cc) * 1024 + sidx];   // 2-way bank alias: free
            o[cc] = f2bf((v - mean) * rstd * ga[cc] + be[cc]);
        }
        *reinterpret_cast<bf16x8*>(out + sidx * 16 + half * 8) = o;
    }
}

// ---------------------------------------------------------------------------
// NT GEMM, 256x256 / 8-wave / two-phase-per-K-tile — EXACT R10 schedule
// (best measured: de-fenced interior, counted vmcnt, one barrier per phase).
// New: HN_A/HN_B flags select blocked-hn addressing for the A/B operand:
//   lane chunk j=(t&7)^(srow&7); addr = ((bz*32 + j/2)*1024 + row)*16 + (j&1)*8
//   row-stride 16, per-K-tile stride 65536. LDS image identical to linear.
// FIFO vmcnt ledger identical to R8/R10 (verified). Both-sides XOR swizzle
// (0 conflicts), XCD-aware grid remap, fused rowsum partials (EXPRS) /
// 4-partial divide (DIVROW4) epilogues.
// ---------------------------------------------------------------------------
template<int BIAS_M, int BIAS_N, int RESID, int EXPRS, int DIVROW4, int HN_A, int HN_B>
__global__ __launch_bounds__(512, 1)
void nt_gemm(const short* __restrict__ A, const short* __restrict__ B,
             void* __restrict__ Cv,
             const float* __restrict__ biasM, const float* __restrict__ biasN,
             const float* __restrict__ resid, float* __restrict__ rs,
             float scale, int K, int lda, int ldb, int ldc,
             long long sA, long long sB, long long sC,
             int tilesM, int tilesPerBatch)
{
    __shared__ short lsA[2][2][128 * 64];   // [buf][Mhalf] 16 KB regions
    __shared__ short lsB[2][2][128 * 64];   // 128 KB total

    const int id = blockIdx.x;
    const int chunk = gridDim.x >> 3;    // grid % 8 == 0 by construction
    const int gid = (id & 7) * chunk + (id >> 3);
    const int bz = gid / tilesPerBatch;
    const int tt = gid - bz * tilesPerBatch;
    const int m0 = (tt % tilesM) * 256;
    const int n0 = (tt / tilesM) * 256;

    const int t = threadIdx.x;           // 0..511
    const int lane = t & 63;
    const int w = t >> 6;                // 0..7
    const int wrs = w >> 1;              // row strip 0..3 (32 rows/quadrant)
    const int wcs = w & 1;               // col strip 0..1 (64 cols/quadrant)
    const int lr16 = lane & 15, lkg = lane >> 4;
    const int sw = lr16 & 7;             // read-side swizzle key (row & 7)

    const int srow = t >> 3;             // 0..63
    const int jch  = (t & 7) ^ (srow & 7);         // pre-swizzled chunk 0..7
    const int scol = jch * 8;

    const short* gA; int rsA, ktA;
    if (HN_A) {
        gA = A + ((long long)bz * 32 + (jch >> 1)) * 16384
               + (long long)(m0 + srow) * 16 + (jch & 1) * 8;
        rsA = 16; ktA = 65536;
    } else {
        gA = A + (long long)bz * sA + (long long)(m0 + srow) * lda + scol;
        rsA = lda; ktA = 64;
    }
    const short* gB; int rsB, ktB;
    if (HN_B) {
        gB = B + ((long long)bz * 32 + (jch >> 1)) * 16384
               + (long long)(n0 + srow) * 16 + (jch & 1) * 8;
        rsB = 16; ktB = 65536;
    } else {
        gB = B + (long long)bz * sB + (long long)(n0 + srow) * ldb + scol;
        rsB = ldb; ktB = 64;
    }

    f32x4 acc[4][2][4];                  // [quadrant ah*2+bh][mi2][ni]
#pragma unroll
    for (int q = 0; q < 4; ++q)
#pragma unroll
        for (int i = 0; i < 2; ++i)
#pragma unroll
            for (int j = 0; j < 4; ++j) acc[q][i][j] = (f32x4){0.f, 0.f, 0.f, 0.f};

    const int nk = K >> 6;               // even (8 or 16)

#define STAGE_A(buf, h, kt)                                                    \
    {                                                                          \
        _Pragma("unroll")                                                      \
        for (int c = 0; c < 2; ++c)                                            \
            __builtin_amdgcn_global_load_lds(                                  \
                (guint*)(gA + (long long)(kt) * ktA                            \
                            + (long long)((h) * 128 + 64 * c) * rsA),          \
                (luint*)&lsA[buf][h][t * 8 + 4096 * c], 16, 0, 0);             \
    }
#define STAGE_B(buf, h, kt)                                                    \
    {                                                                          \
        _Pragma("unroll")                                                      \
        for (int c = 0; c < 2; ++c)                                            \
            __builtin_amdgcn_global_load_lds(                                  \
                (guint*)(gB + (long long)(kt) * ktB                            \
                            + (long long)((h) * 128 + 64 * c) * rsB),          \
                (luint*)&lsB[buf][h][t * 8 + 4096 * c], 16, 0, 0);             \
    }

#define LDA_HALF(dst, buf, h)                                                  \
    _Pragma("unroll")                                                          \
    for (int mi2 = 0; mi2 < 2; ++mi2)                                          \
        _Pragma("unroll")                                                      \
        for (int ks = 0; ks < 2; ++ks)                                         \
            dst[mi2][ks] = *reinterpret_cast<const bf16x8*>(                   \
                &lsA[buf][h][(wrs * 32 + mi2 * 16 + lr16) * 64 +               \
                             (((ks * 4 + lkg) ^ sw) * 8)]);
#define LDB_HALF(dst, buf, h)                                                  \
    _Pragma("unroll")                                                          \
    for (int ni = 0; ni < 4; ++ni)                                             \
        _Pragma("unroll")                                                      \
        for (int ks = 0; ks < 2; ++ks)                                         \
            dst[ni][ks] = *reinterpret_cast<const bf16x8*>(                    \
                &lsB[buf][h][(wcs * 64 + ni * 16 + lr16) * 64 +                \
                             (((ks * 4 + lkg) ^ sw) * 8)]);

#define MFMAQ(q, Af, Bf)                                                       \
    _Pragma("unroll")                                                          \
    for (int ks = 0; ks < 2; ++ks)                                             \
        _Pragma("unroll")                                                      \
        for (int mi2 = 0; mi2 < 2; ++mi2)                                      \
            _Pragma("unroll")                                                  \
            for (int ni = 0; ni < 4; ++ni)                                     \
                acc[q][mi2][ni] = __builtin_amdgcn_mfma_f32_16x16x32_bf16(     \
                    Af[mi2][ks], Bf[ni][ks], acc[q][mi2][ni], 0, 0, 0);

#define PH_END(N)                                                              \
    asm volatile("s_waitcnt vmcnt(" #N ")" ::: "memory");                      \
    __builtin_amdgcn_s_barrier();                                              \
    __builtin_amdgcn_sched_barrier(0)

#define FRAME(b, kt)                                                           \
    {                                                                          \
        bf16x8 a0[2][2], a1[2][2], b0f[4][2], b1f[4][2];                       \
        /* ---- phase A: quadrants (0,0), (0,1) — no internal fences ---- */   \
        LDB_HALF(b0f, b, 0)                                                    \
        LDA_HALF(a0, b, 0)                                                     \
        LDB_HALF(b1f, b, 1)                                                    \
        STAGE_B((b) ^ 1, 0, (kt) + 1);                                         \
        STAGE_B((b) ^ 1, 1, (kt) + 1);                                         \
        STAGE_A((b) ^ 1, 0, (kt) + 1);                                         \
        MFMAQ(0, a0, b0f)                                                      \
        MFMAQ(1, a0, b1f)                                                      \
        PH_END(6);                                                             \
        /* ---- phase B: quadrants (1,0), (1,1) — B frags persist ---- */      \
        LDA_HALF(a1, b, 1)                                                     \
        STAGE_A((b) ^ 1, 1, (kt) + 1);                                         \
        MFMAQ(2, a1, b0f)                                                      \
        MFMAQ(3, a1, b1f)                                                      \
        PH_END(2);                                                             \
    }

    // prologue: tile0's {B0,B1,A0} (6 loads) then {A1} (2 loads); vmcnt(2)
    // confirms the 6, leaves A[0][1] in flight = loop invariant.
    STAGE_B(0, 0, 0); STAGE_B(0, 1, 0); STAGE_A(0, 0, 0);
    STAGE_A(0, 1, 0);
    PH_END(2);

    for (int kt = 0; kt < nk; kt += 2) {
        FRAME(0, kt)
        FRAME(1, kt + 1)
    }
    // (tail frame stages tile nk: overshoot reads land in adjacent allocated
    //  ws regions and are never consumed; lsA[1] scratch below is used only
    //  after a __syncthreads.)
#undef STAGE_A
#undef STAGE_B
#undef LDA_HALF
#undef LDB_HALF
#undef MFMAQ
#undef PH_END
#undef FRAME

    // epilogue: D layout col=lane&15, row=(lane>>4)*4+reg (m89-verified)
    float psum[2][2][4];
    if (EXPRS) {
#pragma unroll
        for (int ah = 0; ah < 2; ++ah)
#pragma unroll
            for (int mi2 = 0; mi2 < 2; ++mi2)
#pragma unroll
                for (int j = 0; j < 4; ++j) psum[ah][mi2][j] = 0.f;
    }
#pragma unroll
    for (int ah = 0; ah < 2; ++ah) {
#pragma unroll
        for (int bh = 0; bh < 2; ++bh) {
#pragma unroll
            for (int mi2 = 0; mi2 < 2; ++mi2) {
                float addm[4], mul[4];
#pragma unroll
                for (int j = 0; j < 4; ++j) {
                    const int rrow = m0 + ah * 128 + wrs * 32 + mi2 * 16 + lkg * 4 + j;
                    addm[j] = BIAS_M ? biasM[rrow] : 0.f;
                    if (DIVROW4) {
                        const float* r4 = rs + (long long)bz * 4096 + rrow;
                        mul[j] = 1.f / (r4[0] + r4[1024] + r4[2048] + r4[3072]);
                    } else mul[j] = 1.f;
                }
#pragma unroll
                for (int ni = 0; ni < 4; ++ni) {
                    const int col = n0 + bh * 128 + wcs * 64 + ni * 16 + lr16;
                    float bn = BIAS_N ? biasN[col] : 0.f;
#pragma unroll
                    for (int j = 0; j < 4; ++j) {
                        const int rrow = m0 + ah * 128 + wrs * 32 + mi2 * 16 + lkg * 4 + j;
                        float v2 = acc[ah * 2 + bh][mi2][ni][j] + addm[j] + bn;
                        v2 *= scale;
                        if (EXPRS) { v2 = __expf(v2 - 8.f); psum[ah][mi2][j] += v2; }
                        if (DIVROW4) v2 *= mul[j];
                        const long long idx = (long long)rrow * ldc + col;
                        if (RESID) {
                            float* Cf = (float*)Cv + (long long)bz * sC;
                            Cf[idx] = v2 + resid[(long long)bz * sC + idx];
                        } else {
                            short* Cs = (short*)Cv + (long long)bz * sC;
                            Cs[idx] = f2bf(v2);
                        }
                    }
                }
            }
        }
    }
    if (EXPRS) {
        // rowsum partials: reduce over lr16 lanes (16 cols each of this
        // wave's 2x64-col strips), combine the two wcs waves via lsA[1]
        // scratch (dead region), write rs4[bz][n0/256][m0 + r].
#pragma unroll
        for (int ah = 0; ah < 2; ++ah)
#pragma unroll
            for (int mi2 = 0; mi2 < 2; ++mi2)
#pragma unroll
                for (int j = 0; j < 4; ++j) {
                    float v = psum[ah][mi2][j];
                    v += __shfl_xor(v, 1); v += __shfl_xor(v, 2);
                    v += __shfl_xor(v, 4); v += __shfl_xor(v, 8);
                    psum[ah][mi2][j] = v;
                }
        float* scr = (float*)&lsA[1][0][0];   // 2KB scratch (loop is done)
        __syncthreads();
        if (lr16 == 0) {
#pragma unroll
            for (int ah = 0; ah < 2; ++ah)
#pragma unroll
                for (int mi2 = 0; mi2 < 2; ++mi2)
#pragma unroll
                    for (int j = 0; j < 4; ++j)
                        scr[wcs * 256 + ah * 128 + wrs * 32 + mi2 * 16 + lkg * 4 + j]
                            = psum[ah][mi2][j];
        }
        __syncthreads();
        if (t < 256)
            rs[(long long)bz * 4096 + (n0 >> 8) * 1024 + m0 + t]
                = scr[t] + scr[256 + t];
    }
}

// ---------------------------------------------------------------------------
extern "C" void kernel_launch(void* const* d_in, const int* in_sizes, int n_in,
                              void* d_out, int out_size, void* d_ws, size_t ws_size,
                              hipStream_t stream)
{
    (void)in_sizes; (void)n_in; (void)out_size; (void)ws_size;
    const float* x     = (const float*)d_in[0];
    const float* gamma = (const float*)d_in[1];
    const float* beta  = (const float*)d_in[2];
    const float* Wq = (const float*)d_in[3];
    const float* bq = (const float*)d_in[4];
    const float* Wk = (const float*)d_in[5];
    const float* bk = (const float*)d_in[6];
    const float* Wv = (const float*)d_in[7];
    const float* bv = (const float*)d_in[8];
    const float* Wp = (const float*)d_in[9];
    const float* bp = (const float*)d_in[10];
    float* out = (float*)d_out;

    // Workspace (time-overlapped), ~162.6 MB:
    //   [0,64M):    expS (b,s,t) bf16; hn (blocked [b][g][s][16c]) bf16 in
    //               [0,32M) dies after the v-GEMM, before scores writes expS.
    //   [64,128M):  qk (b,s,1024) bf16; dies after scores; ho reuses [64,96M).
    //   [128,160M): v (b,c,t) bf16
    //   [160,162M): WT = {WqT*qs, WkT, WvT, WpT} (d,c) bf16
    //   [162M..):   bqk (4K) | rs4 (b,4,1024) f32 (512K)
    char* ws = (char*)d_ws;
    short*  expS = (short*)ws;
    short*  hn   = (short*)ws;
    short*  qkb  = (short*)(ws + (64LL << 20));
    short*  vbuf = (short*)(ws + (128LL << 20));
    short*  wT   = (short*)(ws + (160LL << 20));
    float*  bqk  = (float*)(ws + (162LL << 20) + (16 << 10));
    float*  rs4  = (float*)(ws + (162LL << 20) + (32 << 10));
    short*  ho   = qkb;

    const short* WqkT = wT;                  // rows 0-511: Wq^T*qs; 512-1023: Wk^T
    const short* WvT  = wT + 2 * 512 * 512;
    const short* WpT  = wT + 3 * 512 * 512;

    const float qscale = 0.044194173824159216f;  // 512^-0.5

    transpose_w<<<dim3(16, 16, 4), 256, 0, stream>>>(Wq, Wk, Wv, Wp, wT, qscale);
    concat_bias<<<dim3(4), 256, 0, stream>>>(bq, bk, bqk, qscale);
    gn_fused<<<dim3(1024), 256, 0, stream>>>(x, gamma, beta, hn);

    // qk = hn @ [Wq*qs | Wk] + bqk : M=1024(s), N=1024(d'), K=512 (hn blocked A)
    nt_gemm<0, 1, 0, 0, 0, 1, 0><<<512, 512, 0, stream>>>(
        hn, WqkT, qkb, nullptr, bqk, nullptr, nullptr, 1.f,
        512, 512, 512, 1024, 0, 0, 1024LL * 1024, 4, 16);
    // v (d,t) = WvT @ hn^T + bv : M=512(d), N=1024(t), K=512 (hn blocked B)
    nt_gemm<1, 0, 0, 0, 0, 0, 1><<<256, 512, 0, stream>>>(
        WvT, hn, vbuf, bv, nullptr, nullptr, nullptr, 1.f,
        512, 512, 512, 1024, 0, 0, 512 * 1024, 2, 8);
    // expS (s,t) = exp(q @ k^T - 8) + rs4 partials : M=N=1024, K=512
    nt_gemm<0, 0, 0, 1, 0, 0, 0><<<512, 512, 0, stream>>>(
        qkb, qkb + 512, expS, nullptr, nullptr, nullptr, rs4, 1.f,
        512, 1024, 1024, 1024, 1024LL * 1024, 1024LL * 1024, 1024LL * 1024, 4, 16);
    // ho (s,c) = (expS @ v^T) / rowsum : M=1024(s), N=512(c), K=1024
    nt_gemm<0, 0, 0, 0, 1, 0, 0><<<256, 512, 0, stream>>>(
        expS, vbuf, ho, nullptr, nullptr, nullptr, rs4, 1.f,
        1024, 1024, 1024, 512, 1024LL * 1024, 512 * 1024, 1024 * 512, 4, 8);
    // out (d,s) = WpT @ ho^T + bp + x : M=512(d), N=1024(s), K=512, fp32
    nt_gemm<1, 0, 1, 0, 0, 0, 0><<<256, 512, 0, stream>>>(
        WpT, ho, out, bp, nullptr, x, nullptr, 1.f,
        512, 512, 512, 1024, 0, 1024 * 512, 512LL * 1024, 2, 8);
}